// Round 1
// baseline (833.773 us; speedup 1.0000x reference)
//
#include <hip/hip_runtime.h>
#include <math.h>

#define N_NODES 50000
#define N_EDGES 800000
#define NF 64  // hidden/output feature width of every GCN layer

// ---------------- degree / normalization ----------------

__global__ void init_deg_kernel(float* __restrict__ deg, int n) {
    int i = blockIdx.x * blockDim.x + threadIdx.x;
    if (i < n) deg[i] = 1.0f;  // self-loop contributes 1
}

__global__ void deg_count_kernel(const int* __restrict__ dst, float* __restrict__ deg, int e) {
    int i = blockIdx.x * blockDim.x + threadIdx.x;
    if (i < e) atomicAdd(&deg[dst[i]], 1.0f);
}

__global__ void rsqrt_kernel(float* __restrict__ dis, int n) {
    int i = blockIdx.x * blockDim.x + threadIdx.x;
    if (i < n) dis[i] = rsqrtf(dis[i]);  // deg >= 1 always (self-loops)
}

// ---------------- h' = (X @ W) * dis[row]; also seeds agg with self-loop term ----------------
// One wave (64 lanes) per node row; W staged in LDS; X row broadcast via shfl.

template <int K>
__global__ void gemm_scale_kernel(const float* __restrict__ X, const float* __restrict__ W,
                                  const float* __restrict__ dis, float* __restrict__ h,
                                  float* __restrict__ agg, int n) {
    __shared__ float Wl[K * NF];
    int t = threadIdx.x;
    for (int idx = t * 4; idx < K * NF; idx += 256 * 4) {
        *reinterpret_cast<float4*>(&Wl[idx]) = *reinterpret_cast<const float4*>(&W[idx]);
    }
    __syncthreads();

    int node = blockIdx.x * 4 + (t >> 6);
    int lane = t & 63;
    if (node >= n) return;

    const float* xr = X + (size_t)node * K;
    float acc = 0.0f;
#pragma unroll
    for (int part = 0; part < K / 64; ++part) {
        float xv = xr[part * 64 + lane];  // each lane holds one x element
#pragma unroll
        for (int k = 0; k < 64; ++k) {
            float xs = __shfl(xv, k, 64);                 // broadcast x[node][part*64+k]
            acc += xs * Wl[(part * 64 + k) * NF + lane];  // 2-way bank alias: free
        }
    }
    float v = acc * dis[node];
    size_t o = (size_t)node * NF + lane;
    h[o] = v;    // message payload h'
    agg[o] = v;  // self-loop seed for the scatter target
}

// ---------------- scatter-add over edges: agg[dst] += h'[src] ----------------
// One wave per edge, lane = feature.

__global__ void edge_agg_kernel(const int* __restrict__ ei, const float* __restrict__ h,
                                float* __restrict__ agg, int e) {
    int idx = blockIdx.x * blockDim.x + threadIdx.x;
    int w = idx >> 6;
    if (w >= e) return;
    int lane = idx & 63;
    int src = ei[w];      // edge_index[0][w]
    int dst = ei[e + w];  // edge_index[1][w]
    float v = h[(size_t)src * NF + lane];
    atomicAdd(&agg[(size_t)dst * NF + lane], v);
}

// ---------------- out = agg * dis[row] + b  (+ ReLU) ----------------

__global__ void finalize_kernel(float* __restrict__ agg, const float* __restrict__ dis,
                                const float* __restrict__ b, int n, int do_relu) {
    int idx = blockIdx.x * blockDim.x + threadIdx.x;
    if (idx >= n * NF) return;
    int i = idx >> 6;
    int f = idx & 63;
    float v = agg[idx] * dis[i] + b[f];
    if (do_relu) v = fmaxf(v, 0.0f);
    agg[idx] = v;
}

// ---------------- head: logits = concat(x1,x2,x3) @ Wl + bl; log_softmax ----------------
// One wave per node. Wl staged transposed in LDS ([8][192]) for conflict-free reads.

__global__ void head_kernel(const float* __restrict__ x1, const float* __restrict__ x2,
                            const float* __restrict__ x3, const float* __restrict__ Wl,
                            const float* __restrict__ bl, float* __restrict__ out, int n) {
    __shared__ float Ws[8 * 192];  // Ws[c*192 + j] = Wl[j*8 + c]
    __shared__ float bs[8];
    int t = threadIdx.x;
    for (int idx = t; idx < 8 * 192; idx += 256) {
        int c = idx / 192, j = idx % 192;
        Ws[idx] = Wl[j * 8 + c];
    }
    if (t < 8) bs[t] = bl[t];
    __syncthreads();

    int node = blockIdx.x * 4 + (t >> 6);
    int lane = t & 63;
    if (node >= n) return;

    const float* rows[3] = {x1 + (size_t)node * NF, x2 + (size_t)node * NF,
                            x3 + (size_t)node * NF};
    float acc[8];
#pragma unroll
    for (int c = 0; c < 8; ++c) acc[c] = 0.0f;
#pragma unroll
    for (int p = 0; p < 3; ++p) {
        float v = rows[p][lane];
#pragma unroll
        for (int c = 0; c < 8; ++c) acc[c] += v * Ws[c * 192 + p * 64 + lane];
    }
    // butterfly reduce over 64 lanes -> every lane holds all 8 logits
#pragma unroll
    for (int off = 32; off >= 1; off >>= 1) {
#pragma unroll
        for (int c = 0; c < 8; ++c) acc[c] += __shfl_xor(acc[c], off, 64);
    }
    if (lane < 8) {
        float lg[8];
        float m = -INFINITY;
#pragma unroll
        for (int c = 0; c < 8; ++c) {
            lg[c] = acc[c] + bs[c];
            m = fmaxf(m, lg[c]);
        }
        float s = 0.0f;
#pragma unroll
        for (int c = 0; c < 8; ++c) s += expf(lg[c] - m);
        float lse = m + logf(s);
        out[(size_t)node * 8 + lane] = lg[lane] - lse;
    }
}

// ---------------- launch ----------------

extern "C" void kernel_launch(void* const* d_in, const int* in_sizes, int n_in,
                              void* d_out, int out_size, void* d_ws, size_t ws_size,
                              hipStream_t stream) {
    const float* x = (const float*)d_in[0];
    const int* ei = (const int*)d_in[1];  // [2, E] row-major: [0..E) = src, [E..2E) = dst
    const float* W1 = (const float*)d_in[2];
    const float* b1 = (const float*)d_in[3];
    const float* W2 = (const float*)d_in[4];
    const float* b2 = (const float*)d_in[5];
    const float* W3 = (const float*)d_in[6];
    const float* b3 = (const float*)d_in[7];
    const float* Wl = (const float*)d_in[8];
    const float* bl = (const float*)d_in[9];
    float* out = (float*)d_out;

    const int n = in_sizes[0] / 128;  // 50000
    const int e = in_sizes[1] / 2;    // 800000

    // workspace layout (fp32): dis[n] | tmp[n*64] | x1[n*64] | x2[n*64] | x3[n*64]
    float* dis = (float*)d_ws;
    float* tmp = dis + n;
    float* x1 = tmp + (size_t)n * NF;
    float* x2 = x1 + (size_t)n * NF;
    float* x3 = x2 + (size_t)n * NF;

    const int B = 256;
    dim3 blk(B);

    // normalization coefficients
    init_deg_kernel<<<dim3((n + B - 1) / B), blk, 0, stream>>>(dis, n);
    deg_count_kernel<<<dim3((e + B - 1) / B), blk, 0, stream>>>(ei + e, dis, e);
    rsqrt_kernel<<<dim3((n + B - 1) / B), blk, 0, stream>>>(dis, n);

    dim3 ggemm((n + 3) / 4);
    dim3 gedge(((size_t)e * 64 + B - 1) / B);
    dim3 gfin(((size_t)n * NF + B - 1) / B);

    // layer 1 (K=128, ReLU)
    gemm_scale_kernel<128><<<ggemm, blk, 0, stream>>>(x, W1, dis, tmp, x1, n);
    edge_agg_kernel<<<gedge, blk, 0, stream>>>(ei, tmp, x1, e);
    finalize_kernel<<<gfin, blk, 0, stream>>>(x1, dis, b1, n, 1);

    // layer 2 (K=64, ReLU)
    gemm_scale_kernel<64><<<ggemm, blk, 0, stream>>>(x1, W2, dis, tmp, x2, n);
    edge_agg_kernel<<<gedge, blk, 0, stream>>>(ei, tmp, x2, e);
    finalize_kernel<<<gfin, blk, 0, stream>>>(x2, dis, b2, n, 1);

    // layer 3 (K=64, no ReLU)
    gemm_scale_kernel<64><<<ggemm, blk, 0, stream>>>(x2, W3, dis, tmp, x3, n);
    edge_agg_kernel<<<gedge, blk, 0, stream>>>(ei, tmp, x3, e);
    finalize_kernel<<<gfin, blk, 0, stream>>>(x3, dis, b3, n, 0);

    // head
    head_kernel<<<ggemm, blk, 0, stream>>>(x1, x2, x3, Wl, bl, out, n);
}

// Round 2
// 478.719 us; speedup vs baseline: 1.7417x; 1.7417x over previous
//
#include <hip/hip_runtime.h>
#include <math.h>

#define NF 64  // feature width of every GCN layer output

// ================= CSR build =================

__global__ void zero_int_kernel(int* __restrict__ p, int n) {
    int i = blockIdx.x * blockDim.x + threadIdx.x;
    if (i < n) p[i] = 0;
}

__global__ void hist_kernel(const int* __restrict__ dst, int* __restrict__ counts, int e) {
    int i = blockIdx.x * blockDim.x + threadIdx.x;
    if (i < e) atomicAdd(&counts[dst[i]], 1);
}

__global__ void dis_kernel(const int* __restrict__ counts, float* __restrict__ dis, int n) {
    int i = blockIdx.x * blockDim.x + threadIdx.x;
    if (i < n) dis[i] = rsqrtf((float)counts[i] + 1.0f);  // +1 = self-loop
}

// per-1024-block exclusive scan of counts -> row_ptr, block totals -> bsums
__global__ void block_scan_kernel(const int* __restrict__ counts, int* __restrict__ row_ptr,
                                  int* __restrict__ bsums, int n) {
    __shared__ int s[1024];
    int t = threadIdx.x;
    int g = blockIdx.x * 1024 + t;
    int v = (g < n) ? counts[g] : 0;
    s[t] = v;
    __syncthreads();
#pragma unroll
    for (int off = 1; off < 1024; off <<= 1) {
        int add = (t >= off) ? s[t - off] : 0;
        __syncthreads();
        s[t] += add;
        __syncthreads();
    }
    if (g < n) row_ptr[g] = s[t] - v;  // exclusive
    if (t == 1023) bsums[blockIdx.x] = s[t];
}

// single-wave scan of block sums (nb <= 64) -> exclusive block offsets in place
__global__ void scan_bsums_kernel(int* __restrict__ bsums, int nb) {
    int t = threadIdx.x;  // blockDim = 64
    int v = (t < nb) ? bsums[t] : 0;
    int orig = v;
#pragma unroll
    for (int off = 1; off < 64; off <<= 1) {
        int u = __shfl_up(v, off, 64);
        if (t >= off) v += u;
    }
    if (t < nb) bsums[t] = v - orig;  // exclusive
}

__global__ void add_offsets_kernel(int* __restrict__ row_ptr, const int* __restrict__ bsums,
                                   int* __restrict__ cursor, int n, int e) {
    int g = blockIdx.x * blockDim.x + threadIdx.x;
    if (g < n) {
        int r = row_ptr[g] + bsums[g >> 10];
        row_ptr[g] = r;
        cursor[g] = r;
    }
    if (g == 0) row_ptr[n] = e;
}

__global__ void fill_kernel(const int* __restrict__ ei, int* __restrict__ cursor,
                            int* __restrict__ col, int e) {
    int i = blockIdx.x * blockDim.x + threadIdx.x;
    if (i < e) {
        int d = ei[e + i];  // dst
        int j = atomicAdd(&cursor[d], 1);
        col[j] = ei[i];  // src
    }
}

// ================= h' = (X @ W) * dis[row] =================
// One wave per node row; W staged in LDS; X row broadcast via shfl.

template <int K>
__global__ void gemm_scale_kernel(const float* __restrict__ X, const float* __restrict__ W,
                                  const float* __restrict__ dis, float* __restrict__ h, int n) {
    __shared__ float Wl[K * NF];
    int t = threadIdx.x;
    for (int idx = t * 4; idx < K * NF; idx += 256 * 4) {
        *reinterpret_cast<float4*>(&Wl[idx]) = *reinterpret_cast<const float4*>(&W[idx]);
    }
    __syncthreads();

    int node = blockIdx.x * 4 + (t >> 6);
    int lane = t & 63;
    if (node >= n) return;

    const float* xr = X + (size_t)node * K;
    float acc = 0.0f;
#pragma unroll
    for (int part = 0; part < K / 64; ++part) {
        float xv = xr[part * 64 + lane];
#pragma unroll
        for (int k = 0; k < 64; ++k) {
            float xs = __shfl(xv, k, 64);
            acc += xs * Wl[(part * 64 + k) * NF + lane];
        }
    }
    h[(size_t)node * NF + lane] = acc * dis[node];
}

// ================= pull aggregation (fused finalize) =================
// out[v] = relu?( (h'[v] + sum_{s in N(v)} h'[s]) * dis[v] + b )
// One wave per node, lane = feature; 4-deep unrolled gather for MLP latency.

__global__ void pull_agg_kernel(const int* __restrict__ row_ptr, const int* __restrict__ col,
                                const float* __restrict__ h, const float* __restrict__ dis,
                                const float* __restrict__ b, float* __restrict__ out, int n,
                                int do_relu) {
    int t = threadIdx.x;
    int node = blockIdx.x * 4 + (t >> 6);
    int lane = t & 63;
    if (node >= n) return;

    int beg = row_ptr[node];
    int end = row_ptr[node + 1];
    float v = h[(size_t)node * NF + lane];  // self-loop

    int j = beg;
    for (; j + 4 <= end; j += 4) {
        int s0 = col[j], s1 = col[j + 1], s2 = col[j + 2], s3 = col[j + 3];
        float a0 = h[(size_t)s0 * NF + lane];
        float a1 = h[(size_t)s1 * NF + lane];
        float a2 = h[(size_t)s2 * NF + lane];
        float a3 = h[(size_t)s3 * NF + lane];
        v += a0 + a1 + a2 + a3;
    }
    for (; j < end; ++j) v += h[(size_t)col[j] * NF + lane];

    float r = v * dis[node] + b[lane];
    if (do_relu) r = fmaxf(r, 0.0f);
    out[(size_t)node * NF + lane] = r;
}

// ================= head =================

__global__ void head_kernel(const float* __restrict__ x1, const float* __restrict__ x2,
                            const float* __restrict__ x3, const float* __restrict__ Wl,
                            const float* __restrict__ bl, float* __restrict__ out, int n) {
    __shared__ float Ws[8 * 192];  // Ws[c*192 + j] = Wl[j*8 + c]
    __shared__ float bs[8];
    int t = threadIdx.x;
    for (int idx = t; idx < 8 * 192; idx += 256) {
        int c = idx / 192, j = idx % 192;
        Ws[idx] = Wl[j * 8 + c];
    }
    if (t < 8) bs[t] = bl[t];
    __syncthreads();

    int node = blockIdx.x * 4 + (t >> 6);
    int lane = t & 63;
    if (node >= n) return;

    const float* rows[3] = {x1 + (size_t)node * NF, x2 + (size_t)node * NF,
                            x3 + (size_t)node * NF};
    float acc[8];
#pragma unroll
    for (int c = 0; c < 8; ++c) acc[c] = 0.0f;
#pragma unroll
    for (int p = 0; p < 3; ++p) {
        float v = rows[p][lane];
#pragma unroll
        for (int c = 0; c < 8; ++c) acc[c] += v * Ws[c * 192 + p * 64 + lane];
    }
#pragma unroll
    for (int off = 32; off >= 1; off >>= 1) {
#pragma unroll
        for (int c = 0; c < 8; ++c) acc[c] += __shfl_xor(acc[c], off, 64);
    }
    if (lane < 8) {
        float lg[8];
        float m = -INFINITY;
#pragma unroll
        for (int c = 0; c < 8; ++c) {
            lg[c] = acc[c] + bs[c];
            m = fmaxf(m, lg[c]);
        }
        float s = 0.0f;
#pragma unroll
        for (int c = 0; c < 8; ++c) s += expf(lg[c] - m);
        float lse = m + logf(s);
        out[(size_t)node * 8 + lane] = lg[lane] - lse;
    }
}

// ================= launch =================

extern "C" void kernel_launch(void* const* d_in, const int* in_sizes, int n_in,
                              void* d_out, int out_size, void* d_ws, size_t ws_size,
                              hipStream_t stream) {
    const float* x = (const float*)d_in[0];
    const int* ei = (const int*)d_in[1];  // [2,E]: [0..E)=src, [E..2E)=dst
    const float* W1 = (const float*)d_in[2];
    const float* b1 = (const float*)d_in[3];
    const float* W2 = (const float*)d_in[4];
    const float* b2 = (const float*)d_in[5];
    const float* W3 = (const float*)d_in[6];
    const float* b3 = (const float*)d_in[7];
    const float* Wl = (const float*)d_in[8];
    const float* bl = (const float*)d_in[9];
    float* out = (float*)d_out;

    const int n = in_sizes[0] / 128;  // 50000
    const int e = in_sizes[1] / 2;    // 800000

    // ws layout: dis[n] f32 | row_ptr[n+1] | cursor[n] | bsums[64] | col[e] |
    //            tmp[n*64] f32 | x1 | x2 | x3 (n*64 f32 each)
    float* dis = (float*)d_ws;
    int* row_ptr = (int*)(dis + n);
    int* cursor = row_ptr + (n + 1);
    int* bsums = cursor + n;
    int* col = bsums + 64;
    float* tmp = (float*)(col + e);
    float* x1 = tmp + (size_t)n * NF;
    float* x2 = x1 + (size_t)n * NF;
    float* x3 = x2 + (size_t)n * NF;

    const int B = 256;
    dim3 blk(B);
    dim3 gn((n + B - 1) / B);
    dim3 ge((e + B - 1) / B);
    const int nb = (n + 1023) / 1024;  // scan blocks (49)

    // ---- CSR build (counts live in `cursor`) ----
    zero_int_kernel<<<gn, blk, 0, stream>>>(cursor, n);
    hist_kernel<<<ge, blk, 0, stream>>>(ei + e, cursor, e);
    dis_kernel<<<gn, blk, 0, stream>>>(cursor, dis, n);
    block_scan_kernel<<<dim3(nb), dim3(1024), 0, stream>>>(cursor, row_ptr, bsums, n);
    scan_bsums_kernel<<<dim3(1), dim3(64), 0, stream>>>(bsums, nb);
    add_offsets_kernel<<<gn, blk, 0, stream>>>(row_ptr, bsums, cursor, n, e);
    fill_kernel<<<ge, blk, 0, stream>>>(ei, cursor, col, e);

    dim3 ggemm((n + 3) / 4);

    // ---- layer 1 (K=128, ReLU) ----
    gemm_scale_kernel<128><<<ggemm, blk, 0, stream>>>(x, W1, dis, tmp, n);
    pull_agg_kernel<<<ggemm, blk, 0, stream>>>(row_ptr, col, tmp, dis, b1, x1, n, 1);

    // ---- layer 2 (K=64, ReLU) ----
    gemm_scale_kernel<64><<<ggemm, blk, 0, stream>>>(x1, W2, dis, tmp, n);
    pull_agg_kernel<<<ggemm, blk, 0, stream>>>(row_ptr, col, tmp, dis, b2, x2, n, 1);

    // ---- layer 3 (K=64, no ReLU) ----
    gemm_scale_kernel<64><<<ggemm, blk, 0, stream>>>(x2, W3, dis, tmp, n);
    pull_agg_kernel<<<ggemm, blk, 0, stream>>>(row_ptr, col, tmp, dis, b3, x3, n, 0);

    // ---- head ----
    head_kernel<<<ggemm, blk, 0, stream>>>(x1, x2, x3, Wl, bl, out, n);
}